// Round 1
// baseline (995.878 us; speedup 1.0000x reference)
//
#include <hip/hip_runtime.h>
#include <stdint.h>

#define B_ 2
#define S_ 2048
#define D_ 4096
#define H_ 32
#define KV_ 8
#define HD_ 128
#define M_ (B_*S_)          // 4096 rows (b*S+s)
#define NQ_ (H_*HD_)        // 4096
#define NKV_ (KV_*HD_)      // 1024

typedef unsigned short u16;
typedef __bf16 bf16x8 __attribute__((ext_vector_type(8)));
typedef float f32x4 __attribute__((ext_vector_type(4)));
typedef u16 u16x8 __attribute__((ext_vector_type(8)));

__device__ __forceinline__ u16 f2bf(float f) {
  union { float f; unsigned u; } v; v.f = f;
  unsigned r = v.u + 0x7fffu + ((v.u >> 16) & 1u);
  return (u16)(r >> 16);
}
__device__ __forceinline__ float bf2f(u16 u) {
  union { unsigned u; float f; } v; v.u = ((unsigned)u) << 16;
  return v.f;
}
__device__ __forceinline__ f32x4 mfma16(bf16x8 a, bf16x8 b, f32x4 c) {
  return __builtin_amdgcn_mfma_f32_16x16x32_bf16(a, b, c, 0, 0, 0);
}

#define GLDS16(gp, lp) __builtin_amdgcn_global_load_lds( \
    (const __attribute__((address_space(1))) unsigned int*)(gp), \
    (__attribute__((address_space(3))) unsigned int*)(lp), 16, 0, 0)

// ---------------- fp32 -> bf16 convert (vectorized) ----------------
__global__ __launch_bounds__(256) void cvt_bf16(const float* __restrict__ in,
                                                u16* __restrict__ out, int n) {
  int i = (blockIdx.x * 256 + threadIdx.x) * 8;
  if (i >= n) return;
  float4 a = *(const float4*)(in + i);
  float4 b = *(const float4*)(in + i + 4);
  u16x8 o;
  o[0]=f2bf(a.x); o[1]=f2bf(a.y); o[2]=f2bf(a.z); o[3]=f2bf(a.w);
  o[4]=f2bf(b.x); o[5]=f2bf(b.y); o[6]=f2bf(b.z); o[7]=f2bf(b.w);
  *(u16x8*)(out + i) = o;
}

// ---------------- transpose + convert: out[c][r] = in[r][c] ----------------
__global__ __launch_bounds__(256) void tcvt(const float* __restrict__ in,
                                            u16* __restrict__ out, int R, int C) {
  __shared__ __attribute__((aligned(16))) u16 tile[32][33];
  int c0 = blockIdx.x * 32, r0 = blockIdx.y * 32;
  int tx = threadIdx.x & 31, ty = threadIdx.x >> 5;
  #pragma unroll
  for (int j = ty; j < 32; j += 8)
    tile[j][tx] = f2bf(in[(size_t)(r0 + j) * C + c0 + tx]);
  __syncthreads();
  #pragma unroll
  for (int j = ty; j < 32; j += 8)
    out[(size_t)(c0 + j) * R + r0 + tx] = tile[tx][j];
}

// ---------------- GEMM: C[M,N] = A[M,K](bf16,row) * BT[N,K](bf16,row)^T ----------------
// 128x128 tile, BK=32, 4 waves 2x2, 16x16x32 MFMA, global_load_lds staging,
// XOR slot swizzle: slot' = slot ^ ((row>>1)&3)  (2-way bank aliasing = free)
template<bool OUTF32>
__global__ __launch_bounds__(256) void gemm_bt(const u16* __restrict__ A,
    const u16* __restrict__ BT, void* __restrict__ Cv, int M, int N, int K) {
  __shared__ __attribute__((aligned(16))) u16 As[128 * 32];
  __shared__ __attribute__((aligned(16))) u16 Bs[128 * 32];
  const int tid = threadIdx.x;
  const int bn0 = blockIdx.x * 128, bm0 = blockIdx.y * 128;
  const int w = tid >> 6, l = tid & 63, g = l >> 4, q = l & 15;
  const int wm = (w >> 1) * 64, wn = (w & 1) * 64;
  f32x4 acc[4][4] = {};
  for (int kt = 0; kt < K; kt += 32) {
    __syncthreads();
    #pragma unroll
    for (int p = 0; p < 2; ++p) {
      int c = tid + p * 256;
      int row = c >> 2, slot = c & 3;
      int srck = (slot ^ ((row >> 1) & 3)) << 3;
      GLDS16(A + (size_t)(bm0 + row) * K + kt + srck, As + c * 8);
      GLDS16(BT + (size_t)(bn0 + row) * K + kt + srck, Bs + c * 8);
    }
    __syncthreads();
    bf16x8 af[4], bfr[4];
    #pragma unroll
    for (int m = 0; m < 4; ++m) {
      int row = wm + m * 16 + q;
      af[m] = *(const bf16x8*)(As + row * 32 + ((g ^ ((row >> 1) & 3)) << 3));
    }
    #pragma unroll
    for (int n = 0; n < 4; ++n) {
      int row = wn + n * 16 + q;
      bfr[n] = *(const bf16x8*)(Bs + row * 32 + ((g ^ ((row >> 1) & 3)) << 3));
    }
    #pragma unroll
    for (int m = 0; m < 4; ++m)
      #pragma unroll
      for (int n = 0; n < 4; ++n)
        acc[m][n] = mfma16(af[m], bfr[n], acc[m][n]);
  }
  #pragma unroll
  for (int m = 0; m < 4; ++m)
    #pragma unroll
    for (int n = 0; n < 4; ++n)
      #pragma unroll
      for (int j = 0; j < 4; ++j) {
        size_t off = (size_t)(bm0 + wm + m * 16 + g * 4 + j) * N + (bn0 + wn + n * 16 + q);
        if (OUTF32) ((float*)Cv)[off] = acc[m][n][j];
        else        ((u16*)Cv)[off]  = f2bf(acc[m][n][j]);
      }
}

// ---------------- RoPE (interleaved pairs, in-place on bf16) ----------------
__global__ __launch_bounds__(256) void rope_kernel(u16* __restrict__ t,
    const float* __restrict__ fc, const float* __restrict__ fs,
    int log2ppr, int total_pairs) {
  int i = blockIdx.x * 256 + threadIdx.x;
  if (i >= total_pairs) return;
  int fi = i & 63;
  int row = i >> log2ppr;           // b*S + s
  int pos = row & (S_ - 1);
  float c = fc[pos * 64 + fi], s = fs[pos * 64 + fi];
  unsigned* p = (unsigned*)(t + 2 * (size_t)i);
  unsigned v = *p;
  float x0 = bf2f((u16)(v & 0xffffu)), x1 = bf2f((u16)(v >> 16));
  float r0 = x0 * c - x1 * s, r1 = x0 * s + x1 * c;
  *p = (unsigned)f2bf(r0) | ((unsigned)f2bf(r1) << 16);
}

// ---------------- causal GQA flash attention ----------------
// block = (qt, h, b), 256 threads = 4 waves; QT=128 (32 q-rows/wave), KT=64.
// Q in regs; K in LDS [64][128] row-XOR-swizzled (gload_lds, pre-swizzled source);
// V^T in LDS [128][72] (reg-staged column loads -> b128 writes);
// scores: D = Q*K^T (16x16x32); softmax online in score layout (shfl_xor over 16 lanes);
// PV: O^T = V^T * P^T  (P via padded LDS round-trip).
__global__ __launch_bounds__(256, 2) void attn_kernel(
    const u16* __restrict__ Qb, const u16* __restrict__ Kb,
    const u16* __restrict__ Vb, u16* __restrict__ Ob) {
  __shared__ __attribute__((aligned(16))) u16 KVs[17408]; // K:8192 + VT:9216 ; reused as [128][136] epilogue scratch
  __shared__ __attribute__((aligned(16))) u16 Ps[4][32 * 72];
  __shared__ float fstat[4][32];
  __shared__ float lstat[4][32];
  u16* Ks  = KVs;          // [64][128]
  u16* VTs = KVs + 8192;   // [128][72]

  const int qt = 15 - (int)blockIdx.x;  // long blocks first
  const int h = blockIdx.y, b = blockIdx.z;
  const int kvh = h >> 2;               // N_REP = 4
  const int tid = threadIdx.x, w = tid >> 6, l = tid & 63, g = l >> 4, q = l & 15;
  const float SL2E = 0.08838834764831845f * 1.4426950408889634f; // scale*log2e

  bf16x8 aq[2][4];
  #pragma unroll
  for (int qb = 0; qb < 2; ++qb)
    #pragma unroll
    for (int kk = 0; kk < 4; ++kk) {
      int srow = qt * 128 + w * 32 + qb * 16 + q;
      aq[qb][kk] = *(const bf16x8*)(Qb + (size_t)(b * S_ + srow) * NQ_ + h * HD_ + kk * 32 + g * 8);
    }

  f32x4 o[2][8] = {};
  float mrow[2][4], lrow[2][4];
  #pragma unroll
  for (int qb = 0; qb < 2; ++qb)
    #pragma unroll
    for (int j = 0; j < 4; ++j) { mrow[qb][j] = -3.0e38f; lrow[qb][j] = 0.f; }

  const int nkt = 2 * qt + 2;
  for (int kt = 0; kt < nkt; ++kt) {
    __syncthreads();
    // stage K (swizzled source -> linear LDS)
    #pragma unroll
    for (int p = 0; p < 4; ++p) {
      int c = tid + p * 256;
      int row = c >> 4, slot = c & 15;
      int srck = (slot ^ (row & 7)) << 3;
      GLDS16(Kb + (size_t)((b * S_ + kt * 64 + row) * KV_ + kvh) * HD_ + srck, Ks + c * 8);
    }
    // stage V^T (column loads, b128 LDS writes)
    #pragma unroll
    for (int p = 0; p < 4; ++p) {
      int idx = tid + p * 256;
      int c = idx & 127, rg = idx >> 7;
      u16x8 vv;
      #pragma unroll
      for (int i2 = 0; i2 < 8; ++i2)
        vv[i2] = Vb[(size_t)((b * S_ + kt * 64 + rg * 8 + i2) * KV_ + kvh) * HD_ + c];
      *(u16x8*)(VTs + c * 72 + rg * 8) = vv;
    }
    __syncthreads();

    if (kt * 64 <= qt * 128 + w * 32 + 31) {   // wave-uniform activity gate
      // ---- QK^T ----
      f32x4 sc[2][4] = {};
      #pragma unroll
      for (int kk = 0; kk < 4; ++kk) {
        bf16x8 bk[4];
        #pragma unroll
        for (int n = 0; n < 4; ++n) {
          int row = n * 16 + q;
          bk[n] = *(const bf16x8*)(Ks + row * 128 + (((kk * 4 + g) ^ (row & 7)) << 3));
        }
        #pragma unroll
        for (int qb = 0; qb < 2; ++qb)
          #pragma unroll
          for (int n = 0; n < 4; ++n)
            sc[qb][n] = mfma16(aq[qb][kk], bk[n], sc[qb][n]);
      }
      // ---- causal mask (only near diagonal; wave-uniform branch) ----
      if (kt * 64 + 63 > qt * 128 + w * 32) {
        #pragma unroll
        for (int qb = 0; qb < 2; ++qb)
          #pragma unroll
          for (int n = 0; n < 4; ++n)
            #pragma unroll
            for (int j = 0; j < 4; ++j) {
              int kglob = kt * 64 + n * 16 + q;
              int qglob = qt * 128 + w * 32 + qb * 16 + g * 4 + j;
              if (kglob > qglob) sc[qb][n][j] = -3.0e38f;
            }
      }
      // ---- online softmax ----
      float fct[2][4];
      #pragma unroll
      for (int qb = 0; qb < 2; ++qb)
        #pragma unroll
        for (int j = 0; j < 4; ++j) {
          float mx = fmaxf(fmaxf(sc[qb][0][j], sc[qb][1][j]),
                           fmaxf(sc[qb][2][j], sc[qb][3][j]));
          mx = fmaxf(mx, __shfl_xor(mx, 1));
          mx = fmaxf(mx, __shfl_xor(mx, 2));
          mx = fmaxf(mx, __shfl_xor(mx, 4));
          mx = fmaxf(mx, __shfl_xor(mx, 8));
          float mnew = fmaxf(mrow[qb][j], mx);
          float f = exp2f((mrow[qb][j] - mnew) * SL2E);
          float rs = 0.f;
          #pragma unroll
          for (int n = 0; n < 4; ++n) {
            float pv = exp2f((sc[qb][n][j] - mnew) * SL2E);
            sc[qb][n][j] = pv; rs += pv;
          }
          rs += __shfl_xor(rs, 1); rs += __shfl_xor(rs, 2);
          rs += __shfl_xor(rs, 4); rs += __shfl_xor(rs, 8);
          lrow[qb][j] = lrow[qb][j] * f + rs;
          mrow[qb][j] = mnew;
          fct[qb][j] = f;
        }
      if (q == 0) {
        #pragma unroll
        for (int qb = 0; qb < 2; ++qb)
          #pragma unroll
          for (int j = 0; j < 4; ++j)
            fstat[w][qb * 16 + g * 4 + j] = fct[qb][j];
      }
      // P -> LDS (bf16, row-major [32][72])
      #pragma unroll
      for (int qb = 0; qb < 2; ++qb)
        #pragma unroll
        for (int n = 0; n < 4; ++n)
          #pragma unroll
          for (int j = 0; j < 4; ++j)
            Ps[w][(qb * 16 + g * 4 + j) * 72 + n * 16 + q] = f2bf(sc[qb][n][j]);
      // rescale O (factor broadcast by q-column via LDS)
      #pragma unroll
      for (int qb = 0; qb < 2; ++qb) {
        float ff = fstat[w][qb * 16 + q];
        #pragma unroll
        for (int m = 0; m < 8; ++m) o[qb][m] *= ff;
      }
      // ---- PV: O^T = V^T * P^T ----
      #pragma unroll
      for (int kk2 = 0; kk2 < 2; ++kk2) {
        bf16x8 bp[2];
        #pragma unroll
        for (int qb = 0; qb < 2; ++qb)
          bp[qb] = *(const bf16x8*)(Ps[w] + (qb * 16 + q) * 72 + kk2 * 32 + g * 8);
        #pragma unroll
        for (int m = 0; m < 8; ++m) {
          bf16x8 av = *(const bf16x8*)(VTs + (m * 16 + q) * 72 + kk2 * 32 + g * 8);
          #pragma unroll
          for (int qb = 0; qb < 2; ++qb)
            o[qb][m] = mfma16(av, bp[qb], o[qb][m]);
        }
      }
    }
  }
  // ---- epilogue: normalize, transpose via LDS, coalesced store ----
  __syncthreads();
  if (q == 0) {
    #pragma unroll
    for (int qb = 0; qb < 2; ++qb)
      #pragma unroll
      for (int j = 0; j < 4; ++j)
        lstat[w][qb * 16 + g * 4 + j] = lrow[qb][j];
  }
  u16* OS = KVs; // [128][136]
  #pragma unroll
  for (int qb = 0; qb < 2; ++qb) {
    float linv = 1.0f / lstat[w][qb * 16 + q];
    #pragma unroll
    for (int m = 0; m < 8; ++m)
      #pragma unroll
      for (int j = 0; j < 4; ++j)
        OS[(w * 32 + qb * 16 + q) * 136 + m * 16 + g * 4 + j] = f2bf(o[qb][m][j] * linv);
  }
  __syncthreads();
  #pragma unroll
  for (int p = 0; p < 8; ++p) {
    int c = tid + p * 256;
    int row = c >> 4, col8 = c & 15;
    u16x8 d = *(const u16x8*)(OS + row * 136 + col8 * 8);
    *(u16x8*)(Ob + (size_t)(b * S_ + qt * 128 + row) * NQ_ + h * HD_ + col8 * 8) = d;
  }
}

extern "C" void kernel_launch(void* const* d_in, const int* in_sizes, int n_in,
                              void* d_out, int out_size, void* d_ws, size_t ws_size,
                              hipStream_t stream) {
  const float* x  = (const float*)d_in[0];
  const float* fc = (const float*)d_in[1];
  const float* fs = (const float*)d_in[2];
  // d_in[3] = mask (causal, applied analytically)
  const float* wq = (const float*)d_in[4];
  const float* wk = (const float*)d_in[5];
  const float* wv = (const float*)d_in[6];
  const float* wo = (const float*)d_in[7];

  char* ws = (char*)d_ws;
  u16* xb  = (u16*)(ws + 0);          // 33554432 B
  u16* wqT = (u16*)(ws + 33554432);   // 33554432
  u16* wkT = (u16*)(ws + 67108864);   // 8388608
  u16* wvT = (u16*)(ws + 75497472);   // 8388608
  u16* woT = (u16*)(ws + 83886080);   // 33554432
  u16* qb  = (u16*)(ws + 117440512);  // 33554432
  u16* kb  = (u16*)(ws + 150994944);  // 8388608
  u16* vb  = (u16*)(ws + 159383552);  // 8388608
  u16* ob  = (u16*)(ws + 167772160);  // 33554432  -> total 201326592
  if (ws_size < 201326592u) return;   // fail loudly rather than corrupt

  cvt_bf16<<<(M_ * D_) / (8 * 256), 256, 0, stream>>>(x, xb, M_ * D_);
  tcvt<<<dim3(NQ_ / 32, D_ / 32), 256, 0, stream>>>(wq, wqT, D_, NQ_);
  tcvt<<<dim3(NKV_ / 32, D_ / 32), 256, 0, stream>>>(wk, wkT, D_, NKV_);
  tcvt<<<dim3(NKV_ / 32, D_ / 32), 256, 0, stream>>>(wv, wvT, D_, NKV_);
  tcvt<<<dim3(D_ / 32, NQ_ / 32), 256, 0, stream>>>(wo, woT, NQ_, D_);

  gemm_bt<false><<<dim3(NQ_ / 128, M_ / 128), 256, 0, stream>>>(xb, wqT, qb, M_, NQ_, D_);
  gemm_bt<false><<<dim3(NKV_ / 128, M_ / 128), 256, 0, stream>>>(xb, wkT, kb, M_, NKV_, D_);
  gemm_bt<false><<<dim3(NKV_ / 128, M_ / 128), 256, 0, stream>>>(xb, wvT, vb, M_, NKV_, D_);

  rope_kernel<<<(M_ * NQ_ / 2) / 256, 256, 0, stream>>>(qb, fc, fs, 11, M_ * NQ_ / 2);
  rope_kernel<<<(M_ * NKV_ / 2) / 256, 256, 0, stream>>>(kb, fc, fs, 9, M_ * NKV_ / 2);

  attn_kernel<<<dim3(S_ / 128, H_, B_), 256, 0, stream>>>(qb, kb, vb, ob);

  gemm_bt<true><<<dim3(D_ / 128, M_ / 128), 256, 0, stream>>>(ob, woT, d_out, M_, D_, NQ_);
}